// Round 1
// baseline (75.780 us; speedup 1.0000x reference)
//
#include <hip/hip_runtime.h>

#define HEADS 8
#define HD 64
#define NB 4          // batch
#define NN 256        // sequence length
#define CC 512        // model dim
#define SCALE 0.125f  // HD^-0.5

// ---------------------------------------------------------------------------
// Kernel 1: QKV projection. y[row][c] = sum_k A[row][k] * W[c][k]
// z = blockIdx.z selects {q,k,v}. Outputs:
//   z=0: qh[(bh*256+n)*64 + d]          (row-major per head)
//   z=1: kT[(bh*64+d)*256 + m]          (transposed per head -> linear LDS stage)
//   z=2: vh[(bh*256+m)*64 + d]          (row-major per head)
// ---------------------------------------------------------------------------
__global__ __launch_bounds__(256) void proj_kernel(
    const float* __restrict__ q, const float* __restrict__ k,
    const float* __restrict__ v, const float* __restrict__ Wq,
    const float* __restrict__ Wk, const float* __restrict__ Wv,
    float* __restrict__ qh, float* __restrict__ kT, float* __restrict__ vh)
{
    const int z = blockIdx.z;
    const float* A = (z == 0) ? q : (z == 1) ? k : v;
    const float* W = (z == 0) ? Wq : (z == 1) ? Wk : Wv;

    const int r0 = blockIdx.x * 64;   // row tile over B*N = 1024
    const int c0 = blockIdx.y * 64;   // col tile over C = 512

    __shared__ float Ast[32][68];     // [kk][row], padded
    __shared__ float Bst[32][68];     // [kk][col], padded

    const int t = threadIdx.x;
    const int tx = t & 15, ty = t >> 4;

    float acc[4][4] = {};

    for (int k0 = 0; k0 < CC; k0 += 32) {
        #pragma unroll
        for (int i = 0; i < 8; ++i) {
            int l = t + i * 256;
            int row = l >> 5, kk = l & 31;
            Ast[kk][row] = A[(r0 + row) * CC + k0 + kk];
        }
        #pragma unroll
        for (int i = 0; i < 8; ++i) {
            int l = t + i * 256;
            int c = l >> 5, kk = l & 31;
            Bst[kk][c] = W[(c0 + c) * CC + k0 + kk];
        }
        __syncthreads();
        #pragma unroll
        for (int kk = 0; kk < 32; ++kk) {
            float4 af = *(const float4*)&Ast[kk][ty * 4];
            float4 bf = *(const float4*)&Bst[kk][tx * 4];
            const float* a = (const float*)&af;
            const float* b = (const float*)&bf;
            #pragma unroll
            for (int i = 0; i < 4; ++i)
                #pragma unroll
                for (int j = 0; j < 4; ++j)
                    acc[i][j] += a[i] * b[j];
        }
        __syncthreads();
    }

    #pragma unroll
    for (int i = 0; i < 4; ++i) {
        int row = r0 + ty * 4 + i;          // = b*256 + n
        int bb = row >> 8, n = row & 255;
        #pragma unroll
        for (int j = 0; j < 4; ++j) {
            int col = c0 + tx * 4 + j;      // = h*64 + d
            int h = col >> 6, d = col & 63;
            int bh = bb * HEADS + h;
            float val = acc[i][j];
            if (z == 0)      qh[(bh * NN + n) * HD + d] = val;
            else if (z == 1) kT[(bh * HD + d) * NN + n] = val;
            else             vh[(bh * NN + n) * HD + d] = val;
        }
    }
}

// ---------------------------------------------------------------------------
// Kernel 2: S = qh @ kh^T * SCALE, softmax, write attn.
// Grid: (8 row-tiles of 32, 32 bh). Wave owns 8 rows; lane owns m=4*lane..+3.
// ---------------------------------------------------------------------------
__global__ __launch_bounds__(256) void qk_kernel(
    const float* __restrict__ qh, const float* __restrict__ kT,
    float* __restrict__ attn)
{
    __shared__ float ks[HD][NN];      // [d][m], 64 KiB

    const int t = threadIdx.x;
    const int lane = t & 63;
    const int wv = __builtin_amdgcn_readfirstlane(t >> 6);
    const int bh = blockIdx.y;
    const int n0 = blockIdx.x * 32;

    // stage K^T slice (linear copy, coalesced, conflict-free)
    {
        const float4* src = (const float4*)(kT + bh * HD * NN);
        float4* dst = (float4*)&ks[0][0];
        #pragma unroll
        for (int i = 0; i < 16; ++i) dst[t + i * 256] = src[t + i * 256];
    }
    __syncthreads();

    float S[8][4] = {};
    const float* qbase = qh + (bh * NN + n0 + wv * 8) * HD;  // wave-uniform

    #pragma unroll
    for (int dc = 0; dc < 16; ++dc) {
        float4 qv[8];
        #pragma unroll
        for (int r = 0; r < 8; ++r)
            qv[r] = *(const float4*)(qbase + r * HD + dc * 4);
        #pragma unroll
        for (int jj = 0; jj < 4; ++jj) {
            float4 kv = *(const float4*)&ks[dc * 4 + jj][4 * lane];
            #pragma unroll
            for (int r = 0; r < 8; ++r) {
                float qs = ((const float*)&qv[r])[jj];
                S[r][0] += qs * kv.x;
                S[r][1] += qs * kv.y;
                S[r][2] += qs * kv.z;
                S[r][3] += qs * kv.w;
            }
        }
    }

    #pragma unroll
    for (int r = 0; r < 8; ++r) {
        float s0 = S[r][0] * SCALE, s1 = S[r][1] * SCALE;
        float s2 = S[r][2] * SCALE, s3 = S[r][3] * SCALE;
        float mx = fmaxf(fmaxf(s0, s1), fmaxf(s2, s3));
        #pragma unroll
        for (int off = 1; off < 64; off <<= 1)
            mx = fmaxf(mx, __shfl_xor(mx, off, 64));
        float e0 = __expf(s0 - mx), e1 = __expf(s1 - mx);
        float e2 = __expf(s2 - mx), e3 = __expf(s3 - mx);
        float sm = (e0 + e1) + (e2 + e3);
        #pragma unroll
        for (int off = 1; off < 64; off <<= 1)
            sm += __shfl_xor(sm, off, 64);
        float inv = 1.0f / sm;
        float4 o = make_float4(e0 * inv, e1 * inv, e2 * inv, e3 * inv);
        int n = n0 + wv * 8 + r;
        *(float4*)(attn + (bh * NN + n) * NN + 4 * lane) = o;
    }
}

// ---------------------------------------------------------------------------
// Kernel 3: x = attn @ vh. Lane owns d; 8 rows per wave amortize LDS reads.
// ---------------------------------------------------------------------------
__global__ __launch_bounds__(256) void pv_kernel(
    const float* __restrict__ vh, const float* __restrict__ attn,
    float* __restrict__ x)
{
    __shared__ float vs[NN][HD];      // [m][d], 64 KiB

    const int t = threadIdx.x;
    const int lane = t & 63;
    const int wv = __builtin_amdgcn_readfirstlane(t >> 6);
    const int bh = blockIdx.y;
    const int bb = bh >> 3, h = bh & 7;
    const int n0 = blockIdx.x * 32;

    {
        const float4* src = (const float4*)(vh + bh * NN * HD);
        float4* dst = (float4*)&vs[0][0];
        #pragma unroll
        for (int i = 0; i < 16; ++i) dst[t + i * 256] = src[t + i * 256];
    }
    __syncthreads();

    const float* pbase = attn + (bh * NN + n0 + wv * 8) * NN;  // wave-uniform
    float acc[8] = {};

    for (int mc = 0; mc < 64; ++mc) {
        float4 pv[8];
        #pragma unroll
        for (int r = 0; r < 8; ++r)
            pv[r] = *(const float4*)(pbase + r * NN + mc * 4);
        #pragma unroll
        for (int j = 0; j < 4; ++j) {
            float vvl = vs[mc * 4 + j][lane];
            #pragma unroll
            for (int r = 0; r < 8; ++r)
                acc[r] += ((const float*)&pv[r])[j] * vvl;
        }
    }

    #pragma unroll
    for (int r = 0; r < 8; ++r) {
        int n = n0 + wv * 8 + r;
        x[(bb * NN + n) * CC + h * HD + lane] = acc[r];
    }
}

// ---------------------------------------------------------------------------
extern "C" void kernel_launch(void* const* d_in, const int* in_sizes, int n_in,
                              void* d_out, int out_size, void* d_ws, size_t ws_size,
                              hipStream_t stream) {
    const float* q  = (const float*)d_in[0];
    const float* k  = (const float*)d_in[1];
    const float* v  = (const float*)d_in[2];
    // d_in[3] relation_feature, d_in[7] W_r_conv, d_in[8] W_r_qk: dead code in ref
    const float* Wq = (const float*)d_in[4];
    const float* Wk = (const float*)d_in[5];
    const float* Wv = (const float*)d_in[6];

    float* x    = (float*)d_out;                  // [4,256,512]
    float* attn = (float*)d_out + 4 * 256 * 512;  // [4,8,256,256]

    float* qh = (float*)d_ws;                     // [32][256][64]
    float* kT = qh + 32 * 256 * 64;               // [32][64][256]
    float* vh = kT + 32 * 256 * 64;               // [32][256][64]

    proj_kernel<<<dim3(16, 8, 3), 256, 0, stream>>>(q, k, v, Wq, Wk, Wv, qh, kT, vh);
    qk_kernel<<<dim3(8, 32), 256, 0, stream>>>(qh, kT, attn);
    pv_kernel<<<dim3(8, 32), 256, 0, stream>>>(vh, attn, x);
}

// Round 2
// 39.587 us; speedup vs baseline: 1.9142x; 1.9142x over previous
//
#include <hip/hip_runtime.h>

#define HEADS 8
#define HD 64
#define NN 256
#define CC 512
#define SCALE 0.125f

typedef _Float16 half4v __attribute__((ext_vector_type(4)));
typedef _Float16 half8v __attribute__((ext_vector_type(8)));
typedef float f32x4 __attribute__((ext_vector_type(4)));

// ---------------------------------------------------------------------------
// Kernel 1: QKV projection via fp16 MFMA. y[tok][ch] = sum_k X[tok][k]*W[ch][k]
// z = 0/1/2 -> q/k/v. Outputs (fp16):
//   z=0: qh[bh][n][d]   z=1: kh[bh][m][d]   z=2: vT[bh][d][m]
// For z<2 we compute D[ch][tok] (A=W, B=X) so the 4 acc rows pack into
// 4 consecutive d's; for z=2 we compute D[tok][ch] (A=X, B=W) so the 4 acc
// rows pack into 4 consecutive m's of vT. Both give one 8B store per frag.
// ---------------------------------------------------------------------------
__global__ __launch_bounds__(256) void proj_kernel(
    const float* __restrict__ q, const float* __restrict__ k,
    const float* __restrict__ v, const float* __restrict__ Wq,
    const float* __restrict__ Wk, const float* __restrict__ Wv,
    _Float16* __restrict__ qh, _Float16* __restrict__ kh,
    _Float16* __restrict__ vT)
{
    const int z = blockIdx.z;
    const float* __restrict__ X = (z == 0) ? q : (z == 1) ? k : v;
    const float* __restrict__ W = (z == 0) ? Wq : (z == 1) ? Wk : Wv;

    const int r0 = blockIdx.x * 128;   // token-row tile (over B*N = 1024)
    const int c0 = blockIdx.y * 128;   // channel-row tile (over C = 512)

    __shared__ _Float16 Xs[128][72];   // +8 halves pad: frag reads 2-way max
    __shared__ _Float16 Ws[128][72];

    const int t = threadIdx.x;
    const int lane = t & 63;
    const int w = t >> 6;
    const int wr = w >> 1, wc = w & 1;
    const int l15 = lane & 15, l4 = lane >> 4;

    const int sc = t & 7;              // k-chunk of 8
    const int sr = t >> 3;             // row 0..31

    f32x4 acc[4][4] = {};

    for (int k0 = 0; k0 < CC; k0 += 64) {
        #pragma unroll
        for (int p = 0; p < 4; ++p) {
            int row = sr + p * 32;
            const float* gx = X + (r0 + row) * CC + k0 + sc * 8;
            const float* gw = W + (c0 + row) * CC + k0 + sc * 8;
            float4 x0 = *(const float4*)gx;
            float4 x1 = *(const float4*)(gx + 4);
            float4 w0 = *(const float4*)gw;
            float4 w1 = *(const float4*)(gw + 4);
            half8v hx, hw;
            hx[0] = (_Float16)x0.x; hx[1] = (_Float16)x0.y;
            hx[2] = (_Float16)x0.z; hx[3] = (_Float16)x0.w;
            hx[4] = (_Float16)x1.x; hx[5] = (_Float16)x1.y;
            hx[6] = (_Float16)x1.z; hx[7] = (_Float16)x1.w;
            hw[0] = (_Float16)w0.x; hw[1] = (_Float16)w0.y;
            hw[2] = (_Float16)w0.z; hw[3] = (_Float16)w0.w;
            hw[4] = (_Float16)w1.x; hw[5] = (_Float16)w1.y;
            hw[6] = (_Float16)w1.z; hw[7] = (_Float16)w1.w;
            *(half8v*)&Xs[row][sc * 8] = hx;
            *(half8v*)&Ws[row][sc * 8] = hw;
        }
        __syncthreads();
        #pragma unroll
        for (int kk = 0; kk < 2; ++kk) {
            half8v af[4], bf[4];
            #pragma unroll
            for (int mi = 0; mi < 4; ++mi) {
                const _Float16* pa = (z == 2)
                    ? &Xs[wr * 64 + mi * 16 + l15][kk * 32 + l4 * 8]
                    : &Ws[wr * 64 + mi * 16 + l15][kk * 32 + l4 * 8];
                af[mi] = *(const half8v*)pa;
            }
            #pragma unroll
            for (int ni = 0; ni < 4; ++ni) {
                const _Float16* pb = (z == 2)
                    ? &Ws[wc * 64 + ni * 16 + l15][kk * 32 + l4 * 8]
                    : &Xs[wc * 64 + ni * 16 + l15][kk * 32 + l4 * 8];
                bf[ni] = *(const half8v*)pb;
            }
            #pragma unroll
            for (int mi = 0; mi < 4; ++mi)
                #pragma unroll
                for (int ni = 0; ni < 4; ++ni)
                    acc[mi][ni] = __builtin_amdgcn_mfma_f32_16x16x32_f16(
                        af[mi], bf[ni], acc[mi][ni], 0, 0, 0);
        }
        __syncthreads();
    }

    #pragma unroll
    for (int mi = 0; mi < 4; ++mi) {
        #pragma unroll
        for (int ni = 0; ni < 4; ++ni) {
            f32x4 a = acc[mi][ni];
            half4v hv;
            hv[0] = (_Float16)a[0]; hv[1] = (_Float16)a[1];
            hv[2] = (_Float16)a[2]; hv[3] = (_Float16)a[3];
            if (z < 2) {
                int ch  = c0 + wr * 64 + mi * 16 + l4 * 4;   // + rr via hv
                int tok = r0 + wc * 64 + ni * 16 + l15;
                int bb = tok >> 8, n = tok & 255, h = ch >> 6, d = ch & 63;
                _Float16* dst = ((z == 0) ? qh : kh)
                              + (((bb * HEADS + h) * NN + n) * HD + d);
                *(half4v*)dst = hv;
            } else {
                int tok = r0 + wr * 64 + mi * 16 + l4 * 4;   // + rr via hv
                int ch  = c0 + wc * 64 + ni * 16 + l15;
                int bb = tok >> 8, m = tok & 255, h = ch >> 6, d = ch & 63;
                _Float16* dst = vT + (((bb * HEADS + h) * HD + d) * NN + m);
                *(half4v*)dst = hv;
            }
        }
    }
}

// ---------------------------------------------------------------------------
// Kernel 2: S = qh kh^T * SCALE, softmax rows, write attn (fp32).
// Grid (4, 32): 4 row-tiles of 64, bh. 4 waves x 16 q-rows. No LDS: frag
// loads hit L2 (qh/kh are 1 MB each) and each wave-load is 2 KB contiguous.
// ---------------------------------------------------------------------------
__global__ __launch_bounds__(256) void qk_kernel(
    const _Float16* __restrict__ qh, const _Float16* __restrict__ kh,
    float* __restrict__ attn)
{
    const int t = threadIdx.x, lane = t & 63;
    const int w = __builtin_amdgcn_readfirstlane(t >> 6);
    const int l15 = lane & 15, l4 = lane >> 4;
    const int bh = blockIdx.y;
    const int n0 = blockIdx.x * 64 + w * 16;

    const _Float16* qb = qh + (bh * NN + n0 + l15) * HD + l4 * 8;
    half8v aq0 = *(const half8v*)qb;
    half8v aq1 = *(const half8v*)(qb + 32);

    f32x4 acc[16] = {};
    const _Float16* kb = kh + (bh * NN + l15) * HD + l4 * 8;
    #pragma unroll
    for (int nf = 0; nf < 16; ++nf) {
        half8v b0 = *(const half8v*)(kb + nf * 16 * HD);
        half8v b1 = *(const half8v*)(kb + nf * 16 * HD + 32);
        acc[nf] = __builtin_amdgcn_mfma_f32_16x16x32_f16(aq0, b0, acc[nf], 0, 0, 0);
        acc[nf] = __builtin_amdgcn_mfma_f32_16x16x32_f16(aq1, b1, acc[nf], 0, 0, 0);
    }

    #pragma unroll
    for (int rr = 0; rr < 4; ++rr) {
        float s[16];
        float mx = -3.0e38f;
        #pragma unroll
        for (int nf = 0; nf < 16; ++nf) {
            s[nf] = acc[nf][rr] * SCALE;
            mx = fmaxf(mx, s[nf]);
        }
        #pragma unroll
        for (int off = 1; off < 16; off <<= 1)
            mx = fmaxf(mx, __shfl_xor(mx, off, 64));
        float sum = 0.f;
        #pragma unroll
        for (int nf = 0; nf < 16; ++nf) {
            s[nf] = __expf(s[nf] - mx);
            sum += s[nf];
        }
        #pragma unroll
        for (int off = 1; off < 16; off <<= 1)
            sum += __shfl_xor(sum, off, 64);
        float inv = 1.0f / sum;
        const int n = n0 + l4 * 4 + rr;
        float* arow = attn + (bh * NN + n) * NN + l15;
        #pragma unroll
        for (int nf = 0; nf < 16; ++nf) arow[nf * 16] = s[nf] * inv;
    }
}

// ---------------------------------------------------------------------------
// Kernel 3: x = attn @ vh. A-frags: attn fp32 -> fp16 in-register.
// B-frags: vT[bh][d][m] direct from global (L2-resident).
// ---------------------------------------------------------------------------
__global__ __launch_bounds__(256) void pv_kernel(
    const float* __restrict__ attn, const _Float16* __restrict__ vT,
    float* __restrict__ x)
{
    const int t = threadIdx.x, lane = t & 63;
    const int w = __builtin_amdgcn_readfirstlane(t >> 6);
    const int l15 = lane & 15, l4 = lane >> 4;
    const int bh = blockIdx.y, bb = bh >> 3, h = bh & 7;
    const int n0 = blockIdx.x * 64 + w * 16;

    f32x4 acc[4] = {};
    const float* pb = attn + (bh * NN + n0 + l15) * NN + l4 * 8;
    const _Float16* vb = vT + (bh * HD + l15) * NN + l4 * 8;

    #pragma unroll
    for (int mt = 0; mt < 8; ++mt) {
        float4 p0 = *(const float4*)(pb + mt * 32);
        float4 p1 = *(const float4*)(pb + mt * 32 + 4);
        half8v ap;
        ap[0] = (_Float16)p0.x; ap[1] = (_Float16)p0.y;
        ap[2] = (_Float16)p0.z; ap[3] = (_Float16)p0.w;
        ap[4] = (_Float16)p1.x; ap[5] = (_Float16)p1.y;
        ap[6] = (_Float16)p1.z; ap[7] = (_Float16)p1.w;
        #pragma unroll
        for (int df = 0; df < 4; ++df) {
            half8v bv = *(const half8v*)(vb + df * 16 * NN + mt * 32);
            acc[df] = __builtin_amdgcn_mfma_f32_16x16x32_f16(ap, bv, acc[df], 0, 0, 0);
        }
    }

    #pragma unroll
    for (int df = 0; df < 4; ++df)
        #pragma unroll
        for (int rr = 0; rr < 4; ++rr)
            x[(bb * NN + n0 + l4 * 4 + rr) * CC + h * HD + df * 16 + l15]
                = acc[df][rr];
}

// ---------------------------------------------------------------------------
extern "C" void kernel_launch(void* const* d_in, const int* in_sizes, int n_in,
                              void* d_out, int out_size, void* d_ws, size_t ws_size,
                              hipStream_t stream) {
    const float* q  = (const float*)d_in[0];
    const float* k  = (const float*)d_in[1];
    const float* v  = (const float*)d_in[2];
    // d_in[3] relation_feature, d_in[7] W_r_conv, d_in[8] W_r_qk: dead in ref
    const float* Wq = (const float*)d_in[4];
    const float* Wk = (const float*)d_in[5];
    const float* Wv = (const float*)d_in[6];

    float* x    = (float*)d_out;                  // [4,256,512]
    float* attn = (float*)d_out + 4 * 256 * 512;  // [4,8,256,256]

    _Float16* qh = (_Float16*)d_ws;               // [32][256][64]
    _Float16* kh = qh + 32 * 256 * 64;            // [32][256][64]
    _Float16* vT = kh + 32 * 256 * 64;            // [32][64][256]

    proj_kernel<<<dim3(8, 4, 3), 256, 0, stream>>>(q, k, v, Wq, Wk, Wv, qh, kh, vT);
    qk_kernel<<<dim3(4, 32), 256, 0, stream>>>(qh, kh, attn);
    pv_kernel<<<dim3(4, 32), 256, 0, stream>>>(attn, vT, x);
}

// Round 3
// 26.734 us; speedup vs baseline: 2.8346x; 1.4808x over previous
//
#include <hip/hip_runtime.h>

#define HEADS 8
#define HD 64
#define NN 256
#define CC 512
#define SCALE 0.125f

typedef _Float16 half4v __attribute__((ext_vector_type(4)));
typedef _Float16 half8v __attribute__((ext_vector_type(8)));
typedef float f32x4 __attribute__((ext_vector_type(4)));

// ---------------------------------------------------------------------------
// Kernel 1: QKV projection via fp16 MFMA. 64x64 tiles, 4 waves, 384 blocks.
//   z=0: qh[bh][n][d]   z=1: kh[bh][m][d]   z=2: vT[bh][d][m]
// z<2: A=W (channel rows), B=X (token rows) -> acc rows pack 4 d's.
// z=2: A=X, B=W -> acc rows pack 4 m's of vT.
// ---------------------------------------------------------------------------
__global__ __launch_bounds__(256) void proj_kernel(
    const float* __restrict__ q, const float* __restrict__ k,
    const float* __restrict__ v, const float* __restrict__ Wq,
    const float* __restrict__ Wk, const float* __restrict__ Wv,
    _Float16* __restrict__ qh, _Float16* __restrict__ kh,
    _Float16* __restrict__ vT)
{
    const int z = blockIdx.z;
    const float* __restrict__ X = (z == 0) ? q : (z == 1) ? k : v;
    const float* __restrict__ W = (z == 0) ? Wq : (z == 1) ? Wk : Wv;

    const int r0 = blockIdx.x * 64;   // token tile (B*N = 1024 -> 16 tiles)
    const int c0 = blockIdx.y * 64;   // channel tile (C = 512 -> 8 tiles)

    __shared__ _Float16 Xs[64][72];
    __shared__ _Float16 Ws[64][72];

    const int t = threadIdx.x;
    const int lane = t & 63;
    const int w = t >> 6;
    const int wr = w >> 1, wc = w & 1;
    const int l15 = lane & 15, g = lane >> 4;
    const int sc = t & 7, sr = t >> 3;   // staging: 8 k-chunks x 32 rows

    f32x4 acc[2][2] = {};

    for (int k0 = 0; k0 < CC; k0 += 64) {
        #pragma unroll
        for (int p = 0; p < 2; ++p) {
            int row = sr + p * 32;
            const float* gx = X + (r0 + row) * CC + k0 + sc * 8;
            const float* gw = W + (c0 + row) * CC + k0 + sc * 8;
            float4 x0 = *(const float4*)gx, x1 = *(const float4*)(gx + 4);
            float4 w0 = *(const float4*)gw, w1 = *(const float4*)(gw + 4);
            half8v hx, hw;
            hx[0] = (_Float16)x0.x; hx[1] = (_Float16)x0.y;
            hx[2] = (_Float16)x0.z; hx[3] = (_Float16)x0.w;
            hx[4] = (_Float16)x1.x; hx[5] = (_Float16)x1.y;
            hx[6] = (_Float16)x1.z; hx[7] = (_Float16)x1.w;
            hw[0] = (_Float16)w0.x; hw[1] = (_Float16)w0.y;
            hw[2] = (_Float16)w0.z; hw[3] = (_Float16)w0.w;
            hw[4] = (_Float16)w1.x; hw[5] = (_Float16)w1.y;
            hw[6] = (_Float16)w1.z; hw[7] = (_Float16)w1.w;
            *(half8v*)&Xs[row][sc * 8] = hx;
            *(half8v*)&Ws[row][sc * 8] = hw;
        }
        __syncthreads();
        #pragma unroll
        for (int kk = 0; kk < 2; ++kk) {
            half8v af[2], bf[2];
            #pragma unroll
            for (int mi = 0; mi < 2; ++mi)
                af[mi] = *(const half8v*)((z == 2)
                    ? &Xs[wr * 32 + mi * 16 + l15][kk * 32 + g * 8]
                    : &Ws[wr * 32 + mi * 16 + l15][kk * 32 + g * 8]);
            #pragma unroll
            for (int ni = 0; ni < 2; ++ni)
                bf[ni] = *(const half8v*)((z == 2)
                    ? &Ws[wc * 32 + ni * 16 + l15][kk * 32 + g * 8]
                    : &Xs[wc * 32 + ni * 16 + l15][kk * 32 + g * 8]);
            #pragma unroll
            for (int mi = 0; mi < 2; ++mi)
                #pragma unroll
                for (int ni = 0; ni < 2; ++ni)
                    acc[mi][ni] = __builtin_amdgcn_mfma_f32_16x16x32_f16(
                        af[mi], bf[ni], acc[mi][ni], 0, 0, 0);
        }
        __syncthreads();
    }

    #pragma unroll
    for (int mi = 0; mi < 2; ++mi) {
        #pragma unroll
        for (int ni = 0; ni < 2; ++ni) {
            f32x4 a = acc[mi][ni];
            half4v hv;
            hv[0] = (_Float16)a[0]; hv[1] = (_Float16)a[1];
            hv[2] = (_Float16)a[2]; hv[3] = (_Float16)a[3];
            if (z < 2) {
                int ch  = c0 + wr * 32 + mi * 16 + g * 4;   // 4 d's via hv
                int tok = r0 + wc * 32 + ni * 16 + l15;
                int bb = tok >> 8, n = tok & 255, h = ch >> 6, d = ch & 63;
                _Float16* dst = ((z == 0) ? qh : kh)
                              + (((bb * HEADS + h) * NN + n) * HD + d);
                *(half4v*)dst = hv;
            } else {
                int tok = r0 + wr * 32 + mi * 16 + g * 4;   // 4 m's via hv
                int ch  = c0 + wc * 32 + ni * 16 + l15;
                int bb = tok >> 8, m = tok & 255, h = ch >> 6, d = ch & 63;
                _Float16* dst = vT + (((bb * HEADS + h) * HD + d) * NN + m);
                *(half4v*)dst = hv;
            }
        }
    }
}

// ---------------------------------------------------------------------------
// Kernel 2: fused S^T = K Q^T, softmax, attn store, x = P V.
// Grid (8, 32), 128 threads (2 waves x 16 q-rows).
// Swapped QK: acc tile nf holds S[m = 16nf + 4g + r][n = n0 + l15].
// Softmax over m = in-lane reduce(64) + shfl_xor(16,32).
// P repacked to PV B-operand layout via wave-local padded LDS transpose.
// ---------------------------------------------------------------------------
__global__ __launch_bounds__(128) void attn_kernel(
    const _Float16* __restrict__ qh, const _Float16* __restrict__ kh,
    const _Float16* __restrict__ vT, float* __restrict__ attn,
    float* __restrict__ x)
{
    __shared__ _Float16 Plds[2][16][NN + 8];

    const int t = threadIdx.x, lane = t & 63;
    const int w = __builtin_amdgcn_readfirstlane(t >> 6);
    const int l15 = lane & 15, g = lane >> 4;
    const int bh = blockIdx.y, bb = bh >> 3, h = bh & 7;
    const int n0 = blockIdx.x * 32 + w * 16;

    // Q as B-operand: lane holds Q[n = n0+l15][dk = g*8 + j]
    const _Float16* qb = qh + (bh * NN + n0 + l15) * HD + g * 8;
    half8v bq0 = *(const half8v*)qb;
    half8v bq1 = *(const half8v*)(qb + 32);

    // S^T: A = K-frags (rows m), B = Q
    f32x4 acc[16] = {};
    const _Float16* kb = kh + (bh * NN + l15) * HD + g * 8;
    #pragma unroll
    for (int nf = 0; nf < 16; ++nf) {
        half8v a0 = *(const half8v*)(kb + nf * 16 * HD);
        half8v a1 = *(const half8v*)(kb + nf * 16 * HD + 32);
        acc[nf] = __builtin_amdgcn_mfma_f32_16x16x32_f16(a0, bq0, acc[nf], 0, 0, 0);
        acc[nf] = __builtin_amdgcn_mfma_f32_16x16x32_f16(a1, bq1, acc[nf], 0, 0, 0);
    }

    // softmax over m for row n = n0 + l15
    float mx = -3.0e38f;
    #pragma unroll
    for (int nf = 0; nf < 16; ++nf)
        #pragma unroll
        for (int r = 0; r < 4; ++r)
            mx = fmaxf(mx, acc[nf][r]);
    mx = fmaxf(mx, __shfl_xor(mx, 16, 64));
    mx = fmaxf(mx, __shfl_xor(mx, 32, 64));
    mx *= SCALE;

    float sum = 0.f;
    #pragma unroll
    for (int nf = 0; nf < 16; ++nf)
        #pragma unroll
        for (int r = 0; r < 4; ++r) {
            float e = __expf(acc[nf][r] * SCALE - mx);
            acc[nf][r] = e;
            sum += e;
        }
    sum += __shfl_xor(sum, 16, 64);
    sum += __shfl_xor(sum, 32, 64);
    const float inv = 1.0f / sum;

    // P^T -> LDS row-major rows n (wave-local; DS ops are wave-in-order)
    #pragma unroll
    for (int nf = 0; nf < 16; ++nf) {
        half4v hv;
        hv[0] = (_Float16)(acc[nf][0] * inv);
        hv[1] = (_Float16)(acc[nf][1] * inv);
        hv[2] = (_Float16)(acc[nf][2] * inv);
        hv[3] = (_Float16)(acc[nf][3] * inv);
        *(half4v*)&Plds[w][l15][nf * 16 + g * 4] = hv;
    }
    asm volatile("s_waitcnt lgkmcnt(0)" ::: "memory");

    // PV B-frags: lane holds P[m = 32mt + g*8 + j][n = n0 + l15]
    half8v pb[8];
    #pragma unroll
    for (int mt = 0; mt < 8; ++mt)
        pb[mt] = *(const half8v*)&Plds[w][l15][mt * 32 + g * 8];

    // attn store (fp32), coalesced: 16 rows x 128B runs
    float* arow = attn + (bh * NN + n0 + l15) * NN;
    #pragma unroll
    for (int mt = 0; mt < 8; ++mt) {
        float4 f0, f1;
        f0.x = (float)pb[mt][0]; f0.y = (float)pb[mt][1];
        f0.z = (float)pb[mt][2]; f0.w = (float)pb[mt][3];
        f1.x = (float)pb[mt][4]; f1.y = (float)pb[mt][5];
        f1.z = (float)pb[mt][6]; f1.w = (float)pb[mt][7];
        *(float4*)(arow + mt * 32 + g * 8) = f0;
        *(float4*)(arow + mt * 32 + g * 8 + 4) = f1;
    }

    // x^T tiles: A = vT-frags (rows d), B = P-frags
    #pragma unroll
    for (int df = 0; df < 4; ++df) {
        f32x4 o = {};
        const _Float16* vb = vT + (bh * HD + df * 16 + l15) * NN + g * 8;
        #pragma unroll
        for (int mt = 0; mt < 8; ++mt) {
            half8v av = *(const half8v*)(vb + mt * 32);
            o = __builtin_amdgcn_mfma_f32_16x16x32_f16(av, pb[mt], o, 0, 0, 0);
        }
        #pragma unroll
        for (int r = 0; r < 4; ++r)
            x[(bb * NN + n0 + l15) * CC + h * HD + df * 16 + g * 4 + r] = o[r];
    }
}

// ---------------------------------------------------------------------------
extern "C" void kernel_launch(void* const* d_in, const int* in_sizes, int n_in,
                              void* d_out, int out_size, void* d_ws, size_t ws_size,
                              hipStream_t stream) {
    const float* q  = (const float*)d_in[0];
    const float* k  = (const float*)d_in[1];
    const float* v  = (const float*)d_in[2];
    // d_in[3] relation_feature, d_in[7] W_r_conv, d_in[8] W_r_qk: dead in ref
    const float* Wq = (const float*)d_in[4];
    const float* Wk = (const float*)d_in[5];
    const float* Wv = (const float*)d_in[6];

    float* x    = (float*)d_out;                  // [4,256,512]
    float* attn = (float*)d_out + 4 * 256 * 512;  // [4,8,256,256]

    _Float16* qh = (_Float16*)d_ws;               // [32][256][64]
    _Float16* kh = qh + 32 * 256 * 64;            // [32][256][64]
    _Float16* vT = kh + 32 * 256 * 64;            // [32][64][256]

    proj_kernel<<<dim3(16, 8, 3), 256, 0, stream>>>(q, k, v, Wq, Wk, Wv, qh, kh, vT);
    attn_kernel<<<dim3(8, 32), 128, 0, stream>>>(qh, kh, vT, attn, x);
}